// Round 7
// baseline (366.533 us; speedup 1.0000x reference)
//
#include <hip/hip_runtime.h>
#include <cstdint>
#include <cstddef>

// Problem constants
constexpr int B_  = 4;
constexpr int C_  = 512;
constexpr int CH_ = 256;
constexpr int N_  = 4096;
#define LOG2E 1.4426950408889634f

typedef float    f32x4 __attribute__((ext_vector_type(4)));
typedef _Float16 f16x8 __attribute__((ext_vector_type(8)));
typedef _Float16 f16x4 __attribute__((ext_vector_type(4)));

__device__ __forceinline__ f32x4 MFMA16(f16x8 a, f16x8 b, f32x4 c) {
  return __builtin_amdgcn_mfma_f32_16x16x32_f16(a, b, c, 0, 0, 0);
}

// async global->LDS, 16B per lane; LDS dest is wave-uniform base + lane*16
typedef const __attribute__((address_space(1))) unsigned int* gas_u32p;
typedef __attribute__((address_space(3))) unsigned int* las_u32p;
__device__ __forceinline__ void async16(const void* g, void* l) {
  __builtin_amdgcn_global_load_lds((gas_u32p)g, (las_u32p)l, 16, 0, 0);
}

// ---------------------------------------------------------------------------
// Kernel 1: weight prep -> fp16. Wq scaled by LOG2E (softmax in exp2 domain).
// ---------------------------------------------------------------------------
__global__ void prep_w_kernel(const float* __restrict__ Wq,
                              const float* __restrict__ Wk,
                              const float* __restrict__ Wv,
                              _Float16* __restrict__ wq,
                              _Float16* __restrict__ wk,
                              _Float16* __restrict__ wv) {
  int i = blockIdx.x * 256 + threadIdx.x;
  if (i < CH_ * C_) {
    wq[i] = (_Float16)(Wq[i] * LOG2E);
    wk[i] = (_Float16)Wk[i];
  }
  if (i < C_ * C_) wv[i] = (_Float16)Wv[i];
}

// ---------------------------------------------------------------------------
// Kernel 1b: X prep — transpose+cast Q,K,V fp32 [b][c][n] -> fp16 XT[b][n][c].
// 64x64 LDS tile; coalesced reads (256B rows) and writes (128B runs).
// Streaming: 96 MB read + 48 MB write ~= 25-30 us.
// ---------------------------------------------------------------------------
__global__ __launch_bounds__(256) void prep_x_kernel(
    const float* __restrict__ Q, const float* __restrict__ K,
    const float* __restrict__ V, _Float16* __restrict__ XTq,
    _Float16* __restrict__ XTk, _Float16* __restrict__ XTv) {
  __shared__ _Float16 t[64][68];  // pad 68: 8B-aligned f16x4 rows, 2-way banks

  const int z = blockIdx.z;           // b*3 + input
  const int b = z / 3, ip = z - 3 * b;
  const float* X = (ip == 0) ? Q : (ip == 1) ? K : V;
  _Float16* O = (ip == 0) ? XTq : (ip == 1) ? XTk : XTv;

  const int c0 = blockIdx.y * 64, n0 = blockIdx.x * 64;
  const int tid = threadIdx.x;
  const int tr = tid >> 4, tc4 = (tid & 15) * 4;

  const float* Xb = X + (size_t)b * C_ * N_;
#pragma unroll
  for (int it = 0; it < 4; ++it) {
    int c = it * 16 + tr;  // tile-local c row
    f32x4 v = *(const f32x4*)(Xb + (size_t)(c0 + c) * N_ + n0 + tc4);
#pragma unroll
    for (int j = 0; j < 4; ++j) t[tc4 + j][c] = (_Float16)v[j];
  }
  __syncthreads();
  _Float16* Ob = O + (size_t)b * N_ * C_;
#pragma unroll
  for (int it = 0; it < 4; ++it) {
    int n = it * 16 + tr;  // tile-local n row
    f16x4 w = *(const f16x4*)&t[n][tc4];
    *(f16x4*)(Ob + (size_t)(n0 + n) * C_ + c0 + tc4) = w;
  }
}

// ---------------------------------------------------------------------------
// Kernel 2a (NEW): projection GEMM from pre-transposed fp16 XT[b][n][c].
// X staging = attn's proven qT pattern: async16 into linear 4 KB LDS tile,
// XOR-swizzled global source, swizzled b128 fragment reads. The entire
// register X-path (gloadX/writeX/cvt pipeline) is gone; all staging issued
// at step start with full-step cover; one barrier/step.
// LDS = 32 KB (lW dbuf) + 8 KB (lX dbuf) = 40 KB.
// ---------------------------------------------------------------------------
__global__ __launch_bounds__(512, 4) void proj2_kernel(
    const _Float16* __restrict__ wq, const _Float16* __restrict__ wk,
    const _Float16* __restrict__ wv, const _Float16* __restrict__ XTq,
    const _Float16* __restrict__ XTk, const _Float16* __restrict__ XTv,
    const float* __restrict__ bq, const float* __restrict__ bk,
    const float* __restrict__ bv, _Float16* __restrict__ qT,
    _Float16* __restrict__ kT, _Float16* __restrict__ vT) {
  __shared__ __align__(16) _Float16 lW[2][256 * 32];  // 16 KB per buf
  __shared__ __align__(16) _Float16 lX[2][64 * 32];   // [n][c] swizzled, 4 KB

  const int y = blockIdx.y;
  const _Float16* W;
  const _Float16* XT;
  const float* bias;
  _Float16* out;
  int o0 = 0, M, mode;
  float bscale = 1.0f;
  if (y == 0) {
    W = wq; XT = XTq; bias = bq; out = qT; M = CH_; mode = 0; bscale = LOG2E;
  } else if (y == 1) {
    W = wk; XT = XTk; bias = bk; out = kT; M = CH_; mode = 0;
  } else {
    W = wv; XT = XTv; bias = bv; out = vT; M = C_; mode = 1; o0 = (y - 2) * 256;
  }

  const int tid = threadIdx.x;
  const int lane = tid & 63, wave = tid >> 6;
  const int g = lane >> 4, lm = lane & 15;
  const int b = blockIdx.z;
  const int n0 = blockIdx.x * 64;
  const int wo = (wave >> 1) * 64, wn = (wave & 1) * 32;

  const _Float16* Wb = W + (size_t)o0 * C_;
  const _Float16* XTb = XT + (size_t)b * N_ * C_;

  f32x4 acc[8];
#pragma unroll
  for (int i = 0; i < 8; ++i) acc[i] = f32x4{0.f, 0.f, 0.f, 0.f};

  auto stageW = [&](int s, int buf) {
    int c0 = s * 32;
#pragma unroll
    for (int r = 0; r < 2; ++r) {
      int ci = r * 512 + tid;
      int o = ci >> 2, cg = ci & 3;
      async16(Wb + (size_t)o * C_ + c0 + cg * 8,
              (char*)&lW[buf][0] + r * 8192 + wave * 1024);
    }
  };
  // X tile 64n x 32c (4 KB): waves 0-3 issue one async16 each thread.
  // Global source pre-swizzled so the linear LDS layout matches the
  // swizzled fragment reads: slot (rl, cgs) holds c-granule (cgs ^ (rl&3)).
  auto stageX = [&](int s, int buf) {
    if (tid < 256) {
      int rl = tid >> 2, cgs = tid & 3;
      async16(XTb + (size_t)(n0 + rl) * C_ + s * 32 + ((cgs ^ (rl & 3)) * 8),
              (char*)&lX[buf][0] + wave * 1024);
    }
  };

  // prologue
  stageW(0, 0);
  stageX(0, 0);
  __syncthreads();

#pragma unroll
  for (int s = 0; s < 16; ++s) {
    const int cb = s & 1, nb = cb ^ 1;
    if (s < 15) {
      stageW(s + 1, nb);
      stageX(s + 1, nb);
    }

    f16x8 wf[4], xf[2];
#pragma unroll
    for (int ot = 0; ot < 4; ++ot)
      wf[ot] = *(const f16x8*)&lW[cb][((wo + ot * 16 + lm) * 4 + g) * 8];
#pragma unroll
    for (int nt = 0; nt < 2; ++nt) {
      int nl = wn + nt * 16 + lm;
      xf[nt] = *(const f16x8*)&lX[cb][nl * 32 + ((g ^ (nl & 3)) * 8)];
    }

    if (mode == 0) {
#pragma unroll
      for (int nt = 0; nt < 2; ++nt)
#pragma unroll
        for (int ot = 0; ot < 4; ++ot)
          acc[nt * 4 + ot] = MFMA16(xf[nt], wf[ot], acc[nt * 4 + ot]);
    } else {
#pragma unroll
      for (int ot = 0; ot < 4; ++ot)
#pragma unroll
        for (int nt = 0; nt < 2; ++nt)
          acc[ot * 2 + nt] = MFMA16(wf[ot], xf[nt], acc[ot * 2 + nt]);
    }
    __syncthreads();  // drains stage(s+1); all reads of cb done
  }

  if (mode == 0) {
#pragma unroll
    for (int nt = 0; nt < 2; ++nt) {
#pragma unroll
      for (int ot = 0; ot < 4; ++ot) {
        int o = wo + ot * 16 + lm;
        float bv_ = bias[o] * bscale;
#pragma unroll
        for (int r = 0; r < 4; ++r) {
          int n = n0 + wn + nt * 16 + g * 4 + r;
          out[((size_t)b * N_ + n) * M + o] =
              (_Float16)(acc[nt * 4 + ot][r] + bv_);
        }
      }
    }
  } else {
#pragma unroll
    for (int ot = 0; ot < 4; ++ot) {
#pragma unroll
      for (int r = 0; r < 4; ++r) {
        int o = o0 + wo + ot * 16 + g * 4 + r;
        float bv_ = bias[o];
#pragma unroll
        for (int nt = 0; nt < 2; ++nt) {
          int n = n0 + wn + nt * 16 + lm;
          out[((size_t)b * M + o) * N_ + n] =
              (_Float16)(acc[ot * 2 + nt][r] + bv_);
        }
      }
    }
  }
}

// ---------------------------------------------------------------------------
// Kernel 2b (FALLBACK, R6): projection with in-kernel fp32 X transpose.
// Used only if the workspace is too small for the XT buffers.
// ---------------------------------------------------------------------------
__global__ __launch_bounds__(512, 4) void proj_kernel(
    const _Float16* __restrict__ wq, const _Float16* __restrict__ wk,
    const _Float16* __restrict__ wv, const float* __restrict__ Q,
    const float* __restrict__ K, const float* __restrict__ V,
    const float* __restrict__ bq, const float* __restrict__ bk,
    const float* __restrict__ bv, _Float16* __restrict__ qT,
    _Float16* __restrict__ kT, _Float16* __restrict__ vT) {
  __shared__ __align__(16) _Float16 lW[2][256 * 32];
  __shared__ __align__(16) _Float16 lX[2][64 * 56];

  const int y = blockIdx.y;
  const _Float16* W;
  const float* X;
  const float* bias;
  _Float16* out;
  int o0 = 0, M, mode;
  float bscale = 1.0f;
  if (y == 0) {
    W = wq; X = Q; bias = bq; out = qT; M = CH_; mode = 0; bscale = LOG2E;
  } else if (y == 1) {
    W = wk; X = K; bias = bk; out = kT; M = CH_; mode = 0;
  } else {
    W = wv; X = V; bias = bv; out = vT; M = C_; mode = 1; o0 = (y - 2) * 256;
  }

  const int tid = threadIdx.x;
  const int lane = tid & 63, wave = tid >> 6;
  const int g = lane >> 4, lm = lane & 15;
  const int b = blockIdx.z;
  const int n0 = blockIdx.x * 64;
  const int wo = (wave >> 1) * 64, wn = (wave & 1) * 32;

  const _Float16* Wb = W + (size_t)o0 * C_;
  const float* Xb = X + (size_t)b * C_ * N_;

  f32x4 acc[8];
#pragma unroll
  for (int i = 0; i < 8; ++i) acc[i] = f32x4{0.f, 0.f, 0.f, 0.f};

  auto stageW = [&](int s, int buf) {
    int c0 = s * 32;
#pragma unroll
    for (int r = 0; r < 2; ++r) {
      int ci = r * 512 + tid;
      int o = ci >> 2, cg = ci & 3;
      async16(Wb + (size_t)o * C_ + c0 + cg * 8,
              (char*)&lW[buf][0] + r * 8192 + wave * 1024);
    }
  };

  const int xc = tid >> 4;
  const int xn4 = (tid & 15) * 4;
  const int xgran = xc >> 3, xcin = xc & 7;
  auto gloadX = [&](int s) {
    return *(const f32x4*)(Xb + (size_t)(s * 32 + xc) * N_ + n0 + xn4);
  };
  auto writeX = [&](int buf, f32x4 v) {
#pragma unroll
    for (int i = 0; i < 4; ++i) {
      int n = xn4 + i;
      int pos = (xgran ^ ((n >> 2) & 3)) * 8 + xcin;
      lX[buf][n * 56 + pos] = (_Float16)v[i];
    }
  };

  f32x4 xg = gloadX(0);
  writeX(0, xg);
  xg = gloadX(1);
  stageW(0, 0);
  __syncthreads();

#pragma unroll
  for (int s = 0; s < 16; ++s) {
    const int cb = s & 1, nb = cb ^ 1;
    if (s < 15) stageW(s + 1, nb);
    f32x4 xgn;
    if (s < 14) xgn = gloadX(s + 2);

    f16x8 wf[4], xf[2];
#pragma unroll
    for (int ot = 0; ot < 4; ++ot)
      wf[ot] = *(const f16x8*)&lW[cb][((wo + ot * 16 + lm) * 4 + g) * 8];
#pragma unroll
    for (int nt = 0; nt < 2; ++nt) {
      int n = wn + nt * 16 + lm;
      int pos = (g ^ ((n >> 2) & 3)) * 8;
      xf[nt] = *(const f16x8*)&lX[cb][n * 56 + pos];
    }

    if (mode == 0) {
#pragma unroll
      for (int nt = 0; nt < 2; ++nt)
#pragma unroll
        for (int ot = 0; ot < 4; ++ot)
          acc[nt * 4 + ot] = MFMA16(xf[nt], wf[ot], acc[nt * 4 + ot]);
    } else {
#pragma unroll
      for (int ot = 0; ot < 4; ++ot)
#pragma unroll
        for (int nt = 0; nt < 2; ++nt)
          acc[ot * 2 + nt] = MFMA16(wf[ot], xf[nt], acc[ot * 2 + nt]);
    }

    if (s < 15) writeX(nb, xg);
    if (s < 14) xg = xgn;
    __syncthreads();
  }

  if (mode == 0) {
#pragma unroll
    for (int nt = 0; nt < 2; ++nt) {
#pragma unroll
      for (int ot = 0; ot < 4; ++ot) {
        int o = wo + ot * 16 + lm;
        float bv_ = bias[o] * bscale;
#pragma unroll
        for (int r = 0; r < 4; ++r) {
          int n = n0 + wn + nt * 16 + g * 4 + r;
          out[((size_t)b * N_ + n) * M + o] =
              (_Float16)(acc[nt * 4 + ot][r] + bv_);
        }
      }
    }
  } else {
#pragma unroll
    for (int ot = 0; ot < 4; ++ot) {
#pragma unroll
      for (int r = 0; r < 4; ++r) {
        int o = o0 + wo + ot * 16 + g * 4 + r;
        float bv_ = bias[o];
#pragma unroll
        for (int nt = 0; nt < 2; ++nt) {
          int n = n0 + wn + nt * 16 + lm;
          out[((size_t)b * M + o) * N_ + n] =
              (_Float16)(acc[ot * 2 + nt][r] + bv_);
        }
      }
    }
  }
}

// ---------------------------------------------------------------------------
// Kernel 3: flash attention, Q-tile 128, 8 waves, split-K x2 (R3/R6 winner).
// ---------------------------------------------------------------------------
__global__ __launch_bounds__(512, 2) void attn_kernel(
    const _Float16* __restrict__ qT, const _Float16* __restrict__ kT,
    const _Float16* __restrict__ vT, float* __restrict__ Op0,
    _Float16* __restrict__ Op0h, _Float16* __restrict__ Op1,
    float* __restrict__ mbuf, float* __restrict__ lbuf, int op0f16) {
  __shared__ __align__(16) _Float16 kstage[2 * 8192];  // 2 x 16 KB k-tiles
  __shared__ __align__(16) _Float16 P_t[128 * 72];     // P[n][m], stride 72
  __shared__ float al_st[128];
  __shared__ int bumped[8];

  const int tid = threadIdx.x;
  const int lane = tid & 63, wave = tid >> 6;
  const int g = lane >> 4, lm = lane & 15;

  const int bx = blockIdx.x;
  const int xcd = bx & 7;
  const int b = xcd >> 1, h = xcd & 1;
  const int n0 = (bx >> 3) * 128;
  const int mbase = h * 2048;
  const int c0w = wave * 64;

  f32x4 O[4][8];  // [ct][nt]
#pragma unroll
  for (int i = 0; i < 4; ++i)
#pragma unroll
    for (int j = 0; j < 8; ++j) O[i][j] = f32x4{0.f, 0.f, 0.f, 0.f};
  f32x4 Ol = f32x4{0.f, 0.f, 0.f, 0.f};  // l accumulator (ones-MFMA)

  // ---- prologue: q (128 rows x 256 ch) staged in two 64-row rounds ----
  const _Float16* qTb = qT + ((size_t)b * N_ + n0) * CH_;
  f16x8 qf[8];
#pragma unroll
  for (int p = 0; p < 2; ++p) {
#pragma unroll
    for (int r = 0; r < 4; ++r) {
      int sidx = r * 512 + tid;
      int rl = sidx >> 5, cgs = sidx & 31;
      async16(qTb + (size_t)(p * 64 + rl) * CH_ + ((cgs ^ (rl & 7)) * 8),
              (char*)kstage + r * 8192 + wave * 1024);
    }
    __syncthreads();
    if ((wave >> 2) == p) {
      int rl = (wave & 3) * 16 + lm;
#pragma unroll
      for (int ks = 0; ks < 8; ++ks)
        qf[ks] =
            *(const f16x8*)&kstage[rl * 256 + (((ks * 4 + g) ^ (rl & 7)) * 8)];
    }
    __syncthreads();
  }

  const _Float16* kTb = kT + ((size_t)b * N_ + mbase) * CH_;
  auto stage_k = [&](int it) {
    int m0 = it * 32;
    char* dst0 = (char*)kstage + (it & 1) * 16384;
#pragma unroll
    for (int r = 0; r < 2; ++r) {
      int sidx = r * 512 + tid;
      int key = sidx >> 5, cgs = sidx & 31;
      async16(kTb + (size_t)(m0 + key) * CH_ + ((cgs ^ (key & 7)) * 8),
              dst0 + r * 8192 + wave * 1024);
    }
  };
  stage_k(0);

  const _Float16* vTb = vT + (size_t)b * C_ * N_ + mbase;
  const _Float16* vbase[4];
#pragma unroll
  for (int ct = 0; ct < 4; ++ct)
    vbase[ct] = vTb + (size_t)(c0w + ct * 16 + lm) * N_ + g * 8;
  f16x8 vf[4], vfn[4];
#pragma unroll
  for (int ct = 0; ct < 4; ++ct) vf[ct] = *(const f16x8*)vbase[ct];

  float m_run = -1e30f;  // per-lane: running max of THIS lane's row
  f16x8 ones;
#pragma unroll
  for (int i = 0; i < 8; ++i) ones[i] = (_Float16)1.0f;

#pragma unroll 1
  for (int it = 0; it < 64; ++it) {
    __syncthreads();  // T: P_t(it-1) reads done; (it==0) drains stage_k(0)
    if (it < 63) stage_k(it + 1);  // drained at C with S+softmax cover

    // ---- S (SWAPPED): D[key][row]; lane owns keys {4g+r, 16+4g+r} of row
    //      n = wave*16 + lm. ----
    const _Float16* kb = kstage + (it & 1) * 8192;
    f32x4 s0 = f32x4{0.f, 0.f, 0.f, 0.f};
    f32x4 s1 = f32x4{0.f, 0.f, 0.f, 0.f};
    const int key0 = lm, key1 = 16 + lm;
#pragma unroll
    for (int ks = 0; ks < 8; ++ks) {
      f16x8 kf0 =
          *(const f16x8*)&kb[key0 * 256 + (((ks * 4 + g) ^ (key0 & 7)) * 8)];
      f16x8 kf1 =
          *(const f16x8*)&kb[key1 * 256 + (((ks * 4 + g) ^ (key1 & 7)) * 8)];
      s0 = MFMA16(kf0, qf[ks], s0);
      s1 = MFMA16(kf1, qf[ks], s1);
    }

    // ---- row softmax: in-lane max over 8 keys + cross-g reduce ----
    float mx = fmaxf(fmaxf(fmaxf(s0[0], s0[1]), fmaxf(s0[2], s0[3])),
                     fmaxf(fmaxf(s1[0], s1[1]), fmaxf(s1[2], s1[3])));
    mx = fmaxf(mx, __shfl_xor(mx, 16));
    mx = fmaxf(mx, __shfl_xor(mx, 32));
    bool need = (mx > m_run + 8.0f);  // defer-max (T13), exp2 domain
    float mnew = need ? mx : m_run;
    float alpha = need ? exp2f(m_run - mnew) : 1.0f;
    m_run = mnew;
    f16x4 pa, pb;
#pragma unroll
    for (int r = 0; r < 4; ++r) {
      pa[r] = (_Float16)exp2f(s0[r] - mnew);  // bounded by 2^8, fp16-safe
      pb[r] = (_Float16)exp2f(s1[r] - mnew);
    }
    const int prow = wave * 16 + lm;
    *(f16x4*)&P_t[prow * 72 + g * 4] = pa;       // m = 4g..4g+3 (packed b64)
    *(f16x4*)&P_t[prow * 72 + 16 + g * 4] = pb;  // m = 16+4g..16+4g+3
    if (g == 0) al_st[prow] = alpha;
    unsigned long long bal = __ballot(need);
    if (lane == 0) bumped[wave] = (bal != 0ull) ? 1 : 0;
    __syncthreads();  // C: P_t/al_st/bumped visible; drains stage_k(it+1)

    // v prefetch for it+1: drained at next T with rescale+PV cover
    if (it < 63) {
      int mo = (it + 1) * 32;
#pragma unroll
      for (int ct = 0; ct < 4; ++ct)
        vfn[ct] = *(const f16x8*)(vbase[ct] + mo);
    }

    // ---- conditional O-rescale (per row-strip, scalar-branched) ----
#pragma unroll
    for (int nt = 0; nt < 8; ++nt) {
      if (__builtin_amdgcn_readfirstlane(bumped[nt])) {
        float a = al_st[nt * 16 + lm];
#pragma unroll
        for (int ct = 0; ct < 4; ++ct) {
          O[ct][nt][0] *= a; O[ct][nt][1] *= a;
          O[ct][nt][2] *= a; O[ct][nt][3] *= a;
        }
      }
    }
    if (__builtin_amdgcn_readfirstlane(bumped[wave])) {
      float a = al_st[wave * 16 + lm];
      Ol[0] *= a; Ol[1] *= a; Ol[2] *= a; Ol[3] *= a;
    }

    // ---- PV: O^T[c][n] += v[c][m] * P[n][m] ----
#pragma unroll
    for (int nt = 0; nt < 8; ++nt) {
      f16x8 pf = *(const f16x8*)&P_t[(nt * 16 + lm) * 72 + g * 8];
#pragma unroll
      for (int ct = 0; ct < 4; ++ct) O[ct][nt] = MFMA16(vf[ct], pf, O[ct][nt]);
    }
    {  // l for this wave's own 16 rows: D[m][n] = sum_k P[wave*16+n][k]
      f16x8 pfo = *(const f16x8*)&P_t[(wave * 16 + lm) * 72 + g * 8];
      Ol = MFMA16(ones, pfo, Ol);
    }
    if (it < 63) {
#pragma unroll
      for (int ct = 0; ct < 4; ++ct) vf[ct] = vfn[ct];
    }
  }

  // ---- epilogue: partial O + per-row m, l ----
  const size_t hb = (size_t)(b * 2 + h) * N_ + n0;
  if (g == 0) mbuf[hb + wave * 16 + lm] = m_run;
  if (lane < 16) lbuf[hb + wave * 16 + lane] = Ol[0];

  if (h == 0 && !op0f16) {
    float* ob = Op0 + (size_t)b * C_ * N_;
#pragma unroll
    for (int nt = 0; nt < 8; ++nt) {
      int n_g = n0 + nt * 16 + lm;
#pragma unroll
      for (int ct = 0; ct < 4; ++ct) {
        int cb = c0w + ct * 16 + g * 4;
#pragma unroll
        for (int r = 0; r < 4; ++r)
          ob[(size_t)(cb + r) * N_ + n_g] = O[ct][nt][r];
      }
    }
  } else {
    _Float16* ob = (h == 0 ? Op0h : Op1) + (size_t)b * C_ * N_;
#pragma unroll
    for (int nt = 0; nt < 8; ++nt) {
      int n_g = n0 + nt * 16 + lm;
#pragma unroll
      for (int ct = 0; ct < 4; ++ct) {
        int cb = c0w + ct * 16 + g * 4;
#pragma unroll
        for (int r = 0; r < 4; ++r)
          ob[(size_t)(cb + r) * N_ + n_g] = (_Float16)O[ct][nt][r];
      }
    }
  }
}

// ---------------------------------------------------------------------------
// Kernel 4: combine the two K-halves + gamma scale + V residual.
// ---------------------------------------------------------------------------
__global__ __launch_bounds__(256) void combine_kernel(
    float* __restrict__ out, const _Float16* __restrict__ Op0h,
    const _Float16* __restrict__ Op1, const float* __restrict__ mbuf,
    const float* __restrict__ lbuf, const float* __restrict__ Vin,
    const float* __restrict__ gptr, int op0f16) {
  const int b = blockIdx.y;
  const int tid = threadIdx.x;
  const int n = blockIdx.x * 64 + (tid & 15) * 4;
  const int cg = tid >> 4;
  const float gamma = gptr[0];

  float s0[4], s1[4];
#pragma unroll
  for (int j = 0; j < 4; ++j) {
    float m0 = mbuf[(size_t)(b * 2 + 0) * N_ + n + j];
    float m1 = mbuf[(size_t)(b * 2 + 1) * N_ + n + j];
    float mx = fmaxf(m0, m1);
    float a0 = exp2f(m0 - mx), a1 = exp2f(m1 - mx);
    float l = a0 * lbuf[(size_t)(b * 2 + 0) * N_ + n + j] +
              a1 * lbuf[(size_t)(b * 2 + 1) * N_ + n + j];
    float inv = gamma / l;
    s0[j] = a0 * inv;
    s1[j] = a1 * inv;
  }

  const _Float16* O0b = Op0h + (size_t)b * C_ * N_;
  const _Float16* O1b = Op1 + (size_t)b * C_ * N_;
  if (op0f16) {
    for (int c = cg * 32; c < cg * 32 + 32; ++c) {
      size_t idx = ((size_t)b * C_ + c) * N_ + n;
      f16x4 p0 = *(const f16x4*)(O0b + (size_t)c * N_ + n);
      f16x4 p1 = *(const f16x4*)(O1b + (size_t)c * N_ + n);
      f32x4 V = *(const f32x4*)(Vin + idx);
      f32x4 r;
#pragma unroll
      for (int j = 0; j < 4; ++j)
        r[j] = (float)p0[j] * s0[j] + (float)p1[j] * s1[j] + V[j];
      *(f32x4*)(out + idx) = r;
    }
  } else {
    for (int c = cg * 32; c < cg * 32 + 32; ++c) {
      size_t idx = ((size_t)b * C_ + c) * N_ + n;
      f32x4 p0 = *(const f32x4*)(out + idx);
      f16x4 p1 = *(const f16x4*)(O1b + (size_t)c * N_ + n);
      f32x4 V = *(const f32x4*)(Vin + idx);
      f32x4 r;
#pragma unroll
      for (int j = 0; j < 4; ++j)
        r[j] = p0[j] * s0[j] + (float)p1[j] * s1[j] + V[j];
      *(f32x4*)(out + idx) = r;
    }
  }
}

// ---------------------------------------------------------------------------
extern "C" void kernel_launch(void* const* d_in, const int* in_sizes, int n_in,
                              void* d_out, int out_size, void* d_ws, size_t ws_size,
                              hipStream_t stream) {
  const float* Q  = (const float*)d_in[0];
  const float* K  = (const float*)d_in[1];
  const float* V  = (const float*)d_in[2];
  const float* Wq = (const float*)d_in[3];
  const float* bq = (const float*)d_in[4];
  const float* Wk = (const float*)d_in[5];
  const float* bk = (const float*)d_in[6];
  const float* Wv = (const float*)d_in[7];
  const float* bv = (const float*)d_in[8];
  const float* gm = (const float*)d_in[9];
  float* out = (float*)d_out;

  // common carve: weights + projection outputs + m/l
  char* p = (char*)d_ws;
  _Float16* wq = (_Float16*)p; p += (size_t)CH_ * C_ * 2;
  _Float16* wk = (_Float16*)p; p += (size_t)CH_ * C_ * 2;
  _Float16* wv = (_Float16*)p; p += (size_t)C_ * C_ * 2;
  _Float16* qT = (_Float16*)p; p += (size_t)B_ * N_ * CH_ * 2;
  _Float16* kT = (_Float16*)p; p += (size_t)B_ * N_ * CH_ * 2;
  _Float16* vT = (_Float16*)p; p += (size_t)B_ * C_ * N_ * 2;
  float* mbuf = (float*)p; p += (size_t)B_ * 2 * N_ * 4;
  float* lbuf = (float*)p; p += (size_t)B_ * 2 * N_ * 4;

  const size_t xtsz = (size_t)B_ * N_ * C_ * 2;  // 16 MB
  size_t base = (size_t)(p - (char*)d_ws);

  prep_w_kernel<<<(C_ * C_) / 256, 256, 0, stream>>>(Wq, Wk, Wv, wq, wk, wv);

  if (ws_size >= base + 3 * xtsz) {
    // NEW path: pre-transposed fp16 X; XT buffers dead after proj, so the
    // attn partials alias onto them (Op1 := XTq, Op0h := XTk).
    _Float16* XTq = (_Float16*)p;
    _Float16* XTk = (_Float16*)(p + xtsz);
    _Float16* XTv = (_Float16*)(p + 2 * xtsz);
    _Float16* Op1 = XTq;
    _Float16* Op0h = XTk;

    prep_x_kernel<<<dim3(N_ / 64, C_ / 64, B_ * 3), 256, 0, stream>>>(
        Q, K, V, XTq, XTk, XTv);
    proj2_kernel<<<dim3(N_ / 64, 4, B_), 512, 0, stream>>>(
        wq, wk, wv, XTq, XTk, XTv, bq, bk, bv, qT, kT, vT);
    attn_kernel<<<256, 512, 0, stream>>>(qT, kT, vT, out, Op0h, Op1, mbuf,
                                         lbuf, 1);
    combine_kernel<<<dim3(N_ / 64, B_), 256, 0, stream>>>(out, Op0h, Op1, mbuf,
                                                          lbuf, V, gm, 1);
  } else {
    // FALLBACK: R6 layout + in-kernel transpose proj
    _Float16* Op1 = (_Float16*)p; p += (size_t)B_ * C_ * N_ * 2;
    _Float16* Op0h = (_Float16*)p;
    size_t need = (size_t)(p - (char*)d_ws) + (size_t)B_ * C_ * N_ * 2;
    int op0f16 = (ws_size >= need) ? 1 : 0;

    proj_kernel<<<dim3(N_ / 64, 4, B_), 512, 0, stream>>>(
        wq, wk, wv, Q, K, V, bq, bk, bv, qT, kT, vT);
    attn_kernel<<<256, 512, 0, stream>>>(qT, kT, vT, out, Op0h, Op1, mbuf,
                                         lbuf, op0f16);
    combine_kernel<<<dim3(N_ / 64, B_), 256, 0, stream>>>(out, Op0h, Op1, mbuf,
                                                          lbuf, V, gm, op0f16);
  }
}

// Round 9
// 352.980 us; speedup vs baseline: 1.0384x; 1.0384x over previous
//
#include <hip/hip_runtime.h>
#include <cstdint>
#include <cstddef>

// Problem constants
constexpr int B_  = 4;
constexpr int C_  = 512;
constexpr int CH_ = 256;
constexpr int N_  = 4096;
#define LOG2E 1.4426950408889634f

typedef float    f32x4 __attribute__((ext_vector_type(4)));
typedef _Float16 f16x8 __attribute__((ext_vector_type(8)));
typedef _Float16 f16x4 __attribute__((ext_vector_type(4)));

__device__ __forceinline__ f32x4 MFMA16(f16x8 a, f16x8 b, f32x4 c) {
  return __builtin_amdgcn_mfma_f32_16x16x32_f16(a, b, c, 0, 0, 0);
}

// async global->LDS, 16B per lane; LDS dest is wave-uniform base + lane*16
typedef const __attribute__((address_space(1))) unsigned int* gas_u32p;
typedef __attribute__((address_space(3))) unsigned int* las_u32p;
__device__ __forceinline__ void async16(const void* g, void* l) {
  __builtin_amdgcn_global_load_lds((gas_u32p)g, (las_u32p)l, 16, 0, 0);
}

// ---------------------------------------------------------------------------
// Kernel 1: weight prep -> fp16. Wq scaled by LOG2E (softmax in exp2 domain).
// ---------------------------------------------------------------------------
__global__ void prep_w_kernel(const float* __restrict__ Wq,
                              const float* __restrict__ Wk,
                              const float* __restrict__ Wv,
                              _Float16* __restrict__ wq,
                              _Float16* __restrict__ wk,
                              _Float16* __restrict__ wv) {
  int i = blockIdx.x * 256 + threadIdx.x;
  if (i < CH_ * C_) {
    wq[i] = (_Float16)(Wq[i] * LOG2E);
    wk[i] = (_Float16)Wk[i];
  }
  if (i < C_ * C_) wv[i] = (_Float16)Wv[i];
}

// ---------------------------------------------------------------------------
// Kernel 2: fused projection GEMM (q, k, v in one launch; blockIdx.y selects).
// R3/R6 n-tile-64 version (best measured; R4 n32 and R7 prep_x+proj2 both
// regressed — this structure stays).
// ---------------------------------------------------------------------------
__global__ __launch_bounds__(512, 4) void proj_kernel(
    const _Float16* __restrict__ wq, const _Float16* __restrict__ wk,
    const _Float16* __restrict__ wv, const float* __restrict__ Q,
    const float* __restrict__ K, const float* __restrict__ V,
    const float* __restrict__ bq, const float* __restrict__ bk,
    const float* __restrict__ bv, _Float16* __restrict__ qT,
    _Float16* __restrict__ kT, _Float16* __restrict__ vT) {
  __shared__ __align__(16) _Float16 lW[2][256 * 32];  // 16 KB per buf
  __shared__ __align__(16) _Float16 lX[2][64 * 56];   // [n][c] swizzled, 7 KB

  const int y = blockIdx.y;
  const _Float16* W;
  const float* X;
  const float* bias;
  _Float16* out;
  int o0 = 0, M, mode;
  float bscale = 1.0f;
  if (y == 0) {
    W = wq; X = Q; bias = bq; out = qT; M = CH_; mode = 0; bscale = LOG2E;
  } else if (y == 1) {
    W = wk; X = K; bias = bk; out = kT; M = CH_; mode = 0;
  } else {
    W = wv; X = V; bias = bv; out = vT; M = C_; mode = 1; o0 = (y - 2) * 256;
  }

  const int tid = threadIdx.x;
  const int lane = tid & 63, wave = tid >> 6;
  const int g = lane >> 4, lm = lane & 15;
  const int b = blockIdx.z;
  const int n0 = blockIdx.x * 64;
  const int wo = (wave >> 1) * 64, wn = (wave & 1) * 32;

  const _Float16* Wb = W + (size_t)o0 * C_;
  const float* Xb = X + (size_t)b * C_ * N_;

  f32x4 acc[8];
#pragma unroll
  for (int i = 0; i < 8; ++i) acc[i] = f32x4{0.f, 0.f, 0.f, 0.f};

  auto stageW = [&](int s, int buf) {
    int c0 = s * 32;
#pragma unroll
    for (int r = 0; r < 2; ++r) {
      int ci = r * 512 + tid;
      int o = ci >> 2, cg = ci & 3;
      async16(Wb + (size_t)o * C_ + c0 + cg * 8,
              (char*)&lW[buf][0] + r * 8192 + wave * 1024);
    }
  };

  const int xc = tid >> 4;
  const int xn4 = (tid & 15) * 4;
  const int xgran = xc >> 3, xcin = xc & 7;
  auto gloadX = [&](int s) {
    return *(const f32x4*)(Xb + (size_t)(s * 32 + xc) * N_ + n0 + xn4);
  };
  auto writeX = [&](int buf, f32x4 v) {
#pragma unroll
    for (int i = 0; i < 4; ++i) {
      int n = xn4 + i;
      int pos = (xgran ^ ((n >> 2) & 3)) * 8 + xcin;
      lX[buf][n * 56 + pos] = (_Float16)v[i];
    }
  };

  f32x4 xg = gloadX(0);
  writeX(0, xg);
  xg = gloadX(1);
  stageW(0, 0);
  __syncthreads();

#pragma unroll
  for (int s = 0; s < 16; ++s) {
    const int cb = s & 1, nb = cb ^ 1;
    if (s < 15) stageW(s + 1, nb);
    f32x4 xgn;
    if (s < 14) xgn = gloadX(s + 2);

    f16x8 wf[4], xf[2];
#pragma unroll
    for (int ot = 0; ot < 4; ++ot)
      wf[ot] = *(const f16x8*)&lW[cb][((wo + ot * 16 + lm) * 4 + g) * 8];
#pragma unroll
    for (int nt = 0; nt < 2; ++nt) {
      int n = wn + nt * 16 + lm;
      int pos = (g ^ ((n >> 2) & 3)) * 8;
      xf[nt] = *(const f16x8*)&lX[cb][n * 56 + pos];
    }

    if (mode == 0) {
#pragma unroll
      for (int nt = 0; nt < 2; ++nt)
#pragma unroll
        for (int ot = 0; ot < 4; ++ot)
          acc[nt * 4 + ot] = MFMA16(xf[nt], wf[ot], acc[nt * 4 + ot]);
    } else {
#pragma unroll
      for (int ot = 0; ot < 4; ++ot)
#pragma unroll
        for (int nt = 0; nt < 2; ++nt)
          acc[ot * 2 + nt] = MFMA16(wf[ot], xf[nt], acc[ot * 2 + nt]);
    }

    if (s < 15) writeX(nb, xg);  // X(s+1) -> LDS, cover = this step's MFMAs
    if (s < 14) xg = xgn;
    __syncthreads();  // drains stageW(s+1)+gloadX(s+2); writeX visible
  }

  if (mode == 0) {
#pragma unroll
    for (int nt = 0; nt < 2; ++nt) {
#pragma unroll
      for (int ot = 0; ot < 4; ++ot) {
        int o = wo + ot * 16 + lm;
        float bv_ = bias[o] * bscale;
#pragma unroll
        for (int r = 0; r < 4; ++r) {
          int n = n0 + wn + nt * 16 + g * 4 + r;
          out[((size_t)b * N_ + n) * M + o] =
              (_Float16)(acc[nt * 4 + ot][r] + bv_);
        }
      }
    }
  } else {
#pragma unroll
    for (int ot = 0; ot < 4; ++ot) {
#pragma unroll
      for (int r = 0; r < 4; ++r) {
        int o = o0 + wo + ot * 16 + g * 4 + r;
        float bv_ = bias[o];
#pragma unroll
        for (int nt = 0; nt < 2; ++nt) {
          int n = n0 + wn + nt * 16 + lm;
          out[((size_t)b * M + o) * N_ + n] =
              (_Float16)(acc[ot * 2 + nt][r] + bv_);
        }
      }
    }
  }
}

// ---------------------------------------------------------------------------
// Kernel 3: flash attention, Q-tile 128, 8 waves, split-K x2 (R3/R6 winner,
// UNCHANGED — stable at ~187 µs across 4 runs).
// ---------------------------------------------------------------------------
__global__ __launch_bounds__(512, 2) void attn_kernel(
    const _Float16* __restrict__ qT, const _Float16* __restrict__ kT,
    const _Float16* __restrict__ vT, float* __restrict__ Op0,
    _Float16* __restrict__ Op0h, _Float16* __restrict__ Op1,
    float* __restrict__ mbuf, float* __restrict__ lbuf, int op0f16) {
  __shared__ __align__(16) _Float16 kstage[2 * 8192];  // 2 x 16 KB k-tiles
  __shared__ __align__(16) _Float16 P_t[128 * 72];     // P[n][m], stride 72
  __shared__ float al_st[128];
  __shared__ int bumped[8];

  const int tid = threadIdx.x;
  const int lane = tid & 63, wave = tid >> 6;
  const int g = lane >> 4, lm = lane & 15;

  const int bx = blockIdx.x;
  const int xcd = bx & 7;
  const int b = xcd >> 1, h = xcd & 1;
  const int n0 = (bx >> 3) * 128;
  const int mbase = h * 2048;
  const int c0w = wave * 64;

  f32x4 O[4][8];  // [ct][nt]
#pragma unroll
  for (int i = 0; i < 4; ++i)
#pragma unroll
    for (int j = 0; j < 8; ++j) O[i][j] = f32x4{0.f, 0.f, 0.f, 0.f};
  f32x4 Ol = f32x4{0.f, 0.f, 0.f, 0.f};  // l accumulator (ones-MFMA)

  // ---- prologue: q (128 rows x 256 ch) staged in two 64-row rounds ----
  const _Float16* qTb = qT + ((size_t)b * N_ + n0) * CH_;
  f16x8 qf[8];
#pragma unroll
  for (int p = 0; p < 2; ++p) {
#pragma unroll
    for (int r = 0; r < 4; ++r) {
      int sidx = r * 512 + tid;
      int rl = sidx >> 5, cgs = sidx & 31;
      async16(qTb + (size_t)(p * 64 + rl) * CH_ + ((cgs ^ (rl & 7)) * 8),
              (char*)kstage + r * 8192 + wave * 1024);
    }
    __syncthreads();
    if ((wave >> 2) == p) {
      int rl = (wave & 3) * 16 + lm;
#pragma unroll
      for (int ks = 0; ks < 8; ++ks)
        qf[ks] =
            *(const f16x8*)&kstage[rl * 256 + (((ks * 4 + g) ^ (rl & 7)) * 8)];
    }
    __syncthreads();
  }

  const _Float16* kTb = kT + ((size_t)b * N_ + mbase) * CH_;
  auto stage_k = [&](int it) {
    int m0 = it * 32;
    char* dst0 = (char*)kstage + (it & 1) * 16384;
#pragma unroll
    for (int r = 0; r < 2; ++r) {
      int sidx = r * 512 + tid;
      int key = sidx >> 5, cgs = sidx & 31;
      async16(kTb + (size_t)(m0 + key) * CH_ + ((cgs ^ (key & 7)) * 8),
              dst0 + r * 8192 + wave * 1024);
    }
  };
  stage_k(0);

  const _Float16* vTb = vT + (size_t)b * C_ * N_ + mbase;
  const _Float16* vbase[4];
#pragma unroll
  for (int ct = 0; ct < 4; ++ct)
    vbase[ct] = vTb + (size_t)(c0w + ct * 16 + lm) * N_ + g * 8;
  f16x8 vf[4], vfn[4];
#pragma unroll
  for (int ct = 0; ct < 4; ++ct) vf[ct] = *(const f16x8*)vbase[ct];

  float m_run = -1e30f;  // per-lane: running max of THIS lane's row
  f16x8 ones;
#pragma unroll
  for (int i = 0; i < 8; ++i) ones[i] = (_Float16)1.0f;

#pragma unroll 1
  for (int it = 0; it < 64; ++it) {
    __syncthreads();  // T: P_t(it-1) reads done; (it==0) drains stage_k(0)
    if (it < 63) stage_k(it + 1);  // drained at C with S+softmax cover

    // ---- S (SWAPPED): D[key][row]; lane owns keys {4g+r, 16+4g+r} of row
    //      n = wave*16 + lm. ----
    const _Float16* kb = kstage + (it & 1) * 8192;
    f32x4 s0 = f32x4{0.f, 0.f, 0.f, 0.f};
    f32x4 s1 = f32x4{0.f, 0.f, 0.f, 0.f};
    const int key0 = lm, key1 = 16 + lm;
#pragma unroll
    for (int ks = 0; ks < 8; ++ks) {
      f16x8 kf0 =
          *(const f16x8*)&kb[key0 * 256 + (((ks * 4 + g) ^ (key0 & 7)) * 8)];
      f16x8 kf1 =
          *(const f16x8*)&kb[key1 * 256 + (((ks * 4 + g) ^ (key1 & 7)) * 8)];
      s0 = MFMA16(kf0, qf[ks], s0);
      s1 = MFMA16(kf1, qf[ks], s1);
    }

    // ---- row softmax: in-lane max over 8 keys + cross-g reduce ----
    float mx = fmaxf(fmaxf(fmaxf(s0[0], s0[1]), fmaxf(s0[2], s0[3])),
                     fmaxf(fmaxf(s1[0], s1[1]), fmaxf(s1[2], s1[3])));
    mx = fmaxf(mx, __shfl_xor(mx, 16));
    mx = fmaxf(mx, __shfl_xor(mx, 32));
    bool need = (mx > m_run + 8.0f);  // defer-max (T13), exp2 domain
    float mnew = need ? mx : m_run;
    float alpha = need ? exp2f(m_run - mnew) : 1.0f;
    m_run = mnew;
    f16x4 pa, pb;
#pragma unroll
    for (int r = 0; r < 4; ++r) {
      pa[r] = (_Float16)exp2f(s0[r] - mnew);  // bounded by 2^8, fp16-safe
      pb[r] = (_Float16)exp2f(s1[r] - mnew);
    }
    const int prow = wave * 16 + lm;
    *(f16x4*)&P_t[prow * 72 + g * 4] = pa;       // m = 4g..4g+3 (packed b64)
    *(f16x4*)&P_t[prow * 72 + 16 + g * 4] = pb;  // m = 16+4g..16+4g+3
    if (g == 0) al_st[prow] = alpha;
    unsigned long long bal = __ballot(need);
    if (lane == 0) bumped[wave] = (bal != 0ull) ? 1 : 0;
    __syncthreads();  // C: P_t/al_st/bumped visible; drains stage_k(it+1)

    // v prefetch for it+1: drained at next T with rescale+PV cover
    if (it < 63) {
      int mo = (it + 1) * 32;
#pragma unroll
      for (int ct = 0; ct < 4; ++ct)
        vfn[ct] = *(const f16x8*)(vbase[ct] + mo);
    }

    // ---- conditional O-rescale (per row-strip, scalar-branched) ----
#pragma unroll
    for (int nt = 0; nt < 8; ++nt) {
      if (__builtin_amdgcn_readfirstlane(bumped[nt])) {
        float a = al_st[nt * 16 + lm];
#pragma unroll
        for (int ct = 0; ct < 4; ++ct) {
          O[ct][nt][0] *= a; O[ct][nt][1] *= a;
          O[ct][nt][2] *= a; O[ct][nt][3] *= a;
        }
      }
    }
    if (__builtin_amdgcn_readfirstlane(bumped[wave])) {
      float a = al_st[wave * 16 + lm];
      Ol[0] *= a; Ol[1] *= a; Ol[2] *= a; Ol[3] *= a;
    }

    // ---- PV: O^T[c][n] += v[c][m] * P[n][m] ----
#pragma unroll
    for (int nt = 0; nt < 8; ++nt) {
      f16x8 pf = *(const f16x8*)&P_t[(nt * 16 + lm) * 72 + g * 8];
#pragma unroll
      for (int ct = 0; ct < 4; ++ct) O[ct][nt] = MFMA16(vf[ct], pf, O[ct][nt]);
    }
    {  // l for this wave's own 16 rows: D[m][n] = sum_k P[wave*16+n][k]
      f16x8 pfo = *(const f16x8*)&P_t[(wave * 16 + lm) * 72 + g * 8];
      Ol = MFMA16(ones, pfo, Ol);
    }
    if (it < 63) {
#pragma unroll
      for (int ct = 0; ct < 4; ++ct) vf[ct] = vfn[ct];
    }
  }

  // ---- epilogue: partial O + per-row m, l ----
  const size_t hb = (size_t)(b * 2 + h) * N_ + n0;
  if (g == 0) mbuf[hb + wave * 16 + lm] = m_run;
  if (lane < 16) lbuf[hb + wave * 16 + lane] = Ol[0];

  if (h == 0 && !op0f16) {
    float* ob = Op0 + (size_t)b * C_ * N_;
#pragma unroll
    for (int nt = 0; nt < 8; ++nt) {
      int n_g = n0 + nt * 16 + lm;
#pragma unroll
      for (int ct = 0; ct < 4; ++ct) {
        int cb = c0w + ct * 16 + g * 4;
#pragma unroll
        for (int r = 0; r < 4; ++r)
          ob[(size_t)(cb + r) * N_ + n_g] = O[ct][nt][r];
      }
    }
  } else {
    _Float16* ob = (h == 0 ? Op0h : Op1) + (size_t)b * C_ * N_;
#pragma unroll
    for (int nt = 0; nt < 8; ++nt) {
      int n_g = n0 + nt * 16 + lm;
#pragma unroll
      for (int ct = 0; ct < 4; ++ct) {
        int cb = c0w + ct * 16 + g * 4;
#pragma unroll
        for (int r = 0; r < 4; ++r)
          ob[(size_t)(cb + r) * N_ + n_g] = (_Float16)O[ct][nt][r];
      }
    }
  }
}

// ---------------------------------------------------------------------------
// Kernel 4: combine the two K-halves + gamma scale + V residual.
// out = gamma * (a0*O0 + a1*O1) / (a0*l0 + a1*l1) + V
// R8: grid gains a 4-deep c-split (z) -> 1024 blocks = 4 blocks/CU =
// 16 waves/CU (was 1 block/CU = 4 waves/CU, latency-bound for a pure
// 160 MB streaming kernel). Nontemporal loads/stores on the single-touch
// streams (partials, V, out) to avoid L2 thrash.
// ---------------------------------------------------------------------------
__global__ __launch_bounds__(256) void combine_kernel(
    float* __restrict__ out, const _Float16* __restrict__ Op0h,
    const _Float16* __restrict__ Op1, const float* __restrict__ mbuf,
    const float* __restrict__ lbuf, const float* __restrict__ Vin,
    const float* __restrict__ gptr, int op0f16) {
  const int b = blockIdx.y;
  const int cq = blockIdx.z;  // c-quarter: 128 channels per block
  const int tid = threadIdx.x;
  const int n = blockIdx.x * 64 + (tid & 15) * 4;
  const int cg = tid >> 4;
  const float gamma = gptr[0];

  float s0[4], s1[4];
#pragma unroll
  for (int j = 0; j < 4; ++j) {
    float m0 = mbuf[(size_t)(b * 2 + 0) * N_ + n + j];
    float m1 = mbuf[(size_t)(b * 2 + 1) * N_ + n + j];
    float mx = fmaxf(m0, m1);
    float a0 = exp2f(m0 - mx), a1 = exp2f(m1 - mx);
    float l = a0 * lbuf[(size_t)(b * 2 + 0) * N_ + n + j] +
              a1 * lbuf[(size_t)(b * 2 + 1) * N_ + n + j];
    float inv = gamma / l;
    s0[j] = a0 * inv;
    s1[j] = a1 * inv;
  }

  const int cbeg = cq * 128 + cg * 8;  // 8 c per thread
  const _Float16* O0b = Op0h + (size_t)b * C_ * N_;
  const _Float16* O1b = Op1 + (size_t)b * C_ * N_;
  if (op0f16) {
#pragma unroll
    for (int c = cbeg; c < cbeg + 8; ++c) {
      size_t idx = ((size_t)b * C_ + c) * N_ + n;
      f16x4 p0 = __builtin_nontemporal_load((const f16x4*)(O0b + (size_t)c * N_ + n));
      f16x4 p1 = __builtin_nontemporal_load((const f16x4*)(O1b + (size_t)c * N_ + n));
      f32x4 V = __builtin_nontemporal_load((const f32x4*)(Vin + idx));
      f32x4 r;
#pragma unroll
      for (int j = 0; j < 4; ++j)
        r[j] = (float)p0[j] * s0[j] + (float)p1[j] * s1[j] + V[j];
      __builtin_nontemporal_store(r, (f32x4*)(out + idx));
    }
  } else {
#pragma unroll
    for (int c = cbeg; c < cbeg + 8; ++c) {
      size_t idx = ((size_t)b * C_ + c) * N_ + n;
      f32x4 p0 = *(const f32x4*)(out + idx);
      f16x4 p1 = __builtin_nontemporal_load((const f16x4*)(O1b + (size_t)c * N_ + n));
      f32x4 V = __builtin_nontemporal_load((const f32x4*)(Vin + idx));
      f32x4 r;
#pragma unroll
      for (int j = 0; j < 4; ++j)
        r[j] = p0[j] * s0[j] + (float)p1[j] * s1[j] + V[j];
      __builtin_nontemporal_store(r, (f32x4*)(out + idx));
    }
  }
}

// ---------------------------------------------------------------------------
extern "C" void kernel_launch(void* const* d_in, const int* in_sizes, int n_in,
                              void* d_out, int out_size, void* d_ws, size_t ws_size,
                              hipStream_t stream) {
  const float* Q  = (const float*)d_in[0];
  const float* K  = (const float*)d_in[1];
  const float* V  = (const float*)d_in[2];
  const float* Wq = (const float*)d_in[3];
  const float* bq = (const float*)d_in[4];
  const float* Wk = (const float*)d_in[5];
  const float* bk = (const float*)d_in[6];
  const float* Wv = (const float*)d_in[7];
  const float* bv = (const float*)d_in[8];
  const float* gm = (const float*)d_in[9];
  float* out = (float*)d_out;

  // workspace carve (base ~49.5 MB, +16 MB for fp16 Op0 if room)
  char* p = (char*)d_ws;
  _Float16* wq = (_Float16*)p; p += (size_t)CH_ * C_ * 2;
  _Float16* wk = (_Float16*)p; p += (size_t)CH_ * C_ * 2;
  _Float16* wv = (_Float16*)p; p += (size_t)C_ * C_ * 2;
  _Float16* qT = (_Float16*)p; p += (size_t)B_ * N_ * CH_ * 2;
  _Float16* kT = (_Float16*)p; p += (size_t)B_ * N_ * CH_ * 2;
  _Float16* vT = (_Float16*)p; p += (size_t)B_ * C_ * N_ * 2;
  _Float16* Op1 = (_Float16*)p; p += (size_t)B_ * C_ * N_ * 2;  // half-1 partial
  float* mbuf = (float*)p; p += (size_t)B_ * 2 * N_ * 4;
  float* lbuf = (float*)p; p += (size_t)B_ * 2 * N_ * 4;
  _Float16* Op0h = (_Float16*)p;  // half-0 partial (fp16), optional
  size_t need = (size_t)(p - (char*)d_ws) + (size_t)B_ * C_ * N_ * 2;
  int op0f16 = (ws_size >= need) ? 1 : 0;

  prep_w_kernel<<<(C_ * C_) / 256, 256, 0, stream>>>(Wq, Wk, Wv, wq, wk, wv);

  // fused q/k/v projections (y: 0=q, 1=k, 2,3=v halves)
  proj_kernel<<<dim3(N_ / 64, 4, B_), 512, 0, stream>>>(
      wq, wk, wv, Q, K, V, bq, bk, bv, qT, kT, vT);

  // split-K flash attention: half-0 partial -> Op0h (fp16) or d_out (fp32),
  // half-1 -> Op1
  attn_kernel<<<256, 512, 0, stream>>>(qT, kT, vT, out, Op0h, Op1, mbuf, lbuf,
                                       op0f16);

  // 4-deep c-split: 1024 blocks = 4 blocks/CU for latency hiding
  combine_kernel<<<dim3(N_ / 64, B_, 4), 256, 0, stream>>>(out, Op0h, Op1,
                                                           mbuf, lbuf, V, gm,
                                                           op0f16);
}